// Round 3
// baseline (99.778 us; speedup 1.0000x reference)
//
#include <hip/hip_runtime.h>
#include <math.h>

// B=1024, D=128, H=128
#define Bn 1024
#define Dn 128
#define Hn 128

// ---------------- K1: all-pairs partial column sums ----------------
// grid (256 i-tiles, 8 j-slices), 256 threads. 2048 blocks = 8/CU = 32 waves/CU.
// Thread (q = t>>5 in [0,8), c = t&31): accumulates sum_j |x_i - x_j| for
// 4 i-rows, cols 4c..4c+3, over j in [jslice*128 + q*16, +16).
// Per 16B j-load: 32 VALU instrs. LDS-reduce 8 q-groups -> 2KB partial to ws.
__global__ __launch_bounds__(256, 8) void k1_pairs(
    const float* __restrict__ x, float* __restrict__ ws) {
  const int t = threadIdx.x;
  const int c = t & 31;
  const int q = t >> 5;
  const int i0 = blockIdx.x << 2;
  const int jb = (blockIdx.y << 7) + (q << 4);

  __shared__ float red[8][4][Dn];  // 16 KB

  float4 xi[4];
#pragma unroll
  for (int r = 0; r < 4; ++r)
    xi[r] = *(const float4*)(x + (size_t)(i0 + r) * Dn + c * 4);

  float4 acc[4];
#pragma unroll
  for (int r = 0; r < 4; ++r) acc[r] = make_float4(0.f, 0.f, 0.f, 0.f);

  const float4* xq = (const float4*)x + (size_t)jb * (Dn / 4) + c;
#pragma unroll 1
  for (int j = 0; j < 16; j += 2) {
    const float4 xj0 = xq[(size_t)j * (Dn / 4)];
    const float4 xj1 = xq[(size_t)(j + 1) * (Dn / 4)];
#pragma unroll
    for (int r = 0; r < 4; ++r) {
      acc[r].x += fabsf(xi[r].x - xj0.x);
      acc[r].y += fabsf(xi[r].y - xj0.y);
      acc[r].z += fabsf(xi[r].z - xj0.z);
      acc[r].w += fabsf(xi[r].w - xj0.w);
    }
#pragma unroll
    for (int r = 0; r < 4; ++r) {
      acc[r].x += fabsf(xi[r].x - xj1.x);
      acc[r].y += fabsf(xi[r].y - xj1.y);
      acc[r].z += fabsf(xi[r].z - xj1.z);
      acc[r].w += fabsf(xi[r].w - xj1.w);
    }
  }
#pragma unroll
  for (int r = 0; r < 4; ++r) *(float4*)&red[q][r][c * 4] = acc[r];
  __syncthreads();

  // reduce the 8 q-groups; write this block's partial [4][128] to ws
  float* wsp = ws + ((size_t)(blockIdx.x << 3) + blockIdx.y) * 512;
#pragma unroll
  for (int s = t; s < 512; s += 256) {
    float v = 0.f;
#pragma unroll
    for (int qq = 0; qq < 8; ++qq) v += red[qq][s >> 7][s & 127];
    wsp[s] = v;
  }
}

// ---------------- K2: reduce partials + epilogue ----------------
// 256 blocks x 256 threads; block = 4 rows.
__global__ __launch_bounds__(256) void k2_epilogue(
    const float* __restrict__ x, const float* __restrict__ ws,
    const float* __restrict__ Wd, const float* __restrict__ bd,
    const float* __restrict__ Wt, const float* __restrict__ bt,
    const float* __restrict__ Wa, const float* __restrict__ ba,
    const float* __restrict__ Wr, const float* __restrict__ br,
    const float* __restrict__ gamma, const float* __restrict__ beta,
    float* __restrict__ out) {
  const int t = threadIdx.x;
  const int itile = blockIdx.x;
  const int i0 = itile << 2;

  __shared__ float xs[4][Dn];
  __shared__ float dms[4][Dn];
  __shared__ float ms[4][Hn];
  __shared__ float ys[4][Hn];
  __shared__ float wt_s[Dn];
  __shared__ float tau_s[4];  // 1/tau

  // sum the 8 j-slice partials -> dms; stage xs
  const float* wsp = ws + (size_t)(itile << 3) * 512;
#pragma unroll
  for (int s = t; s < 512; s += 256) {
    float v = 0.f;
#pragma unroll
    for (int js = 0; js < 8; ++js) v += wsp[js * 512 + s];
    dms[s >> 7][s & 127] = v * (1.0f / 1024.0f);
    xs[s >> 7][s & 127] = x[((size_t)itile << 9) + s];
  }
  if (t < 128) wt_s[t] = Wt[t];
  __syncthreads();

  // tau (one wave per row)
  {
    const int r = t >> 6, p = t & 63;
    float partial = xs[r][p] * wt_s[p] + xs[r][p + 64] * wt_s[p + 64];
#pragma unroll
    for (int off = 32; off; off >>= 1) partial += __shfl_xor(partial, off, 64);
    if (p == 0) {
      const float z = partial + bt[0];
      const float sp = fmaxf(z, 0.f) + log1pf(expf(-fabsf(z)));  // softplus
      tau_s[r] = 1.0f / (fmaxf(sp, 0.01f) + 1.0f);
    }
  }
  __syncthreads();

  // m = (Wd . dm + bd) / tau
  const int h = t & 127;
  const int g4 = t >> 7;
  const int r0 = 2 * g4, r1 = 2 * g4 + 1;
  {
    float m0 = bd[h], m1 = m0;
    const float4* w = (const float4*)(Wd + (size_t)h * Dn);
#pragma unroll 4
    for (int k4 = 0; k4 < Dn / 4; ++k4) {
      const float4 wv = w[k4];
      const int k = k4 * 4;
      m0 += wv.x * dms[r0][k] + wv.y * dms[r0][k + 1] + wv.z * dms[r0][k + 2] + wv.w * dms[r0][k + 3];
      m1 += wv.x * dms[r1][k] + wv.y * dms[r1][k + 1] + wv.z * dms[r1][k + 2] + wv.w * dms[r1][k + 3];
    }
    ms[r0][h] = m0 * tau_s[r0];
    ms[r1][h] = m1 * tau_s[r1];
  }
  __syncthreads();

  // y = relu(Wa . m + ba) + Wr . x + br
  {
    float q0 = ba[h], q1 = q0, c0 = br[h], c1 = c0;
    const float4* wa = (const float4*)(Wa + (size_t)h * Dn);
    const float4* wr = (const float4*)(Wr + (size_t)h * Dn);
#pragma unroll 4
    for (int k4 = 0; k4 < Dn / 4; ++k4) {
      const float4 av = wa[k4];
      const float4 rv = wr[k4];
      const int k = k4 * 4;
      q0 += av.x * ms[r0][k] + av.y * ms[r0][k + 1] + av.z * ms[r0][k + 2] + av.w * ms[r0][k + 3];
      q1 += av.x * ms[r1][k] + av.y * ms[r1][k + 1] + av.z * ms[r1][k + 2] + av.w * ms[r1][k + 3];
      c0 += rv.x * xs[r0][k] + rv.y * xs[r0][k + 1] + rv.z * xs[r0][k + 2] + rv.w * xs[r0][k + 3];
      c1 += rv.x * xs[r1][k] + rv.y * xs[r1][k + 1] + rv.z * xs[r1][k + 2] + rv.w * xs[r1][k + 3];
    }
    ys[r0][h] = fmaxf(q0, 0.f) + c0;
    ys[r1][h] = fmaxf(q1, 0.f) + c1;
  }
  __syncthreads();

  // LayerNorm (one wave per row)
  {
    const int r = t >> 6, p = t & 63;
    const float v0 = ys[r][p], v1 = ys[r][p + 64];
    float s = v0 + v1;
    float qq = v0 * v0 + v1 * v1;
#pragma unroll
    for (int off = 32; off; off >>= 1) {
      s += __shfl_xor(s, off, 64);
      qq += __shfl_xor(qq, off, 64);
    }
    const float mu = s * (1.0f / 128.0f);
    const float var = qq * (1.0f / 128.0f) - mu * mu;
    const float rs = rsqrtf(var + 1e-5f);
    float* o = out + (size_t)(i0 + r) * Hn;
    o[p]      = (v0 - mu) * rs * gamma[p]      + beta[p];
    o[p + 64] = (v1 - mu) * rs * gamma[p + 64] + beta[p + 64];
  }
}

extern "C" void kernel_launch(void* const* d_in, const int* in_sizes, int n_in,
                              void* d_out, int out_size, void* d_ws, size_t ws_size,
                              hipStream_t stream) {
  const float* x     = (const float*)d_in[0];
  const float* Wd    = (const float*)d_in[1];
  const float* bd    = (const float*)d_in[2];
  const float* Wt    = (const float*)d_in[3];
  const float* bt    = (const float*)d_in[4];
  const float* Wa    = (const float*)d_in[5];
  const float* ba    = (const float*)d_in[6];
  const float* Wr    = (const float*)d_in[7];
  const float* br    = (const float*)d_in[8];
  const float* gamma = (const float*)d_in[9];
  const float* beta  = (const float*)d_in[10];
  float* out = (float*)d_out;
  float* ws = (float*)d_ws;  // needs 256*8*512*4 B = 4 MB

  dim3 g1(Bn / 4, 8);
  k1_pairs<<<g1, 256, 0, stream>>>(x, ws);
  k2_epilogue<<<Bn / 4, 256, 0, stream>>>(x, ws, Wd, bd, Wt, bt, Wa, ba,
                                          Wr, br, gamma, beta, out);
  (void)in_sizes; (void)n_in; (void)out_size; (void)ws_size;
}

// Round 4
// 94.871 us; speedup vs baseline: 1.0517x; 1.0517x over previous
//
#include <hip/hip_runtime.h>
#include <math.h>

// B=1024, D=128, H=128
#define Bn 1024
#define Dn 128
#define Hn 128

// Single fused kernel: 256 blocks x 1024 threads (16 waves/CU, 1 block/CU).
// Phase 1: thread (g = t>>5 in [0,32) -> j in [32g,32g+32), c = t&31 -> cols
//   4c..4c+3) accumulates sum_j |x_i - x_j| for the block's 4 i-rows with
//   float4 loads, 8 loads in flight per wave (128 B -> 256 VALU instrs).
// Phase 2: LDS tree-reduce 32 j-groups -> dms.
// Phase 3: tau per row (wave shuffle reduce), t<256.
// Phase 4: matvecs m=(Wd.dm+bd)/tau ; y=relu(Wa.m+ba)+Wr.x+br, t<256.
// Phase 5: LayerNorm per row, t<256.
__global__ __launch_bounds__(1024) void fused_resd1(
    const float* __restrict__ x,
    const float* __restrict__ Wd, const float* __restrict__ bd,
    const float* __restrict__ Wt, const float* __restrict__ bt,
    const float* __restrict__ Wa, const float* __restrict__ ba,
    const float* __restrict__ Wr, const float* __restrict__ br,
    const float* __restrict__ gamma, const float* __restrict__ beta,
    float* __restrict__ out) {
  const int t = threadIdx.x;
  const int c = t & 31;   // column quad: cols 4c..4c+3
  const int g = t >> 5;   // j-group in [0,32)
  const int i0 = blockIdx.x << 2;

  __shared__ float red[32][4][Dn];  // 64 KB: per-group partial column sums
  __shared__ float xs[4][Dn];
  __shared__ float dms[4][Dn];
  __shared__ float ms[4][Hn];
  __shared__ float ys[4][Hn];
  __shared__ float wt_s[Dn];
  __shared__ float tau_s[4];        // 1/tau

  // ---- Phase 1: all-pairs partial sums, 8 loads in flight ----
  float4 xi[4];
#pragma unroll
  for (int r = 0; r < 4; ++r)
    xi[r] = *(const float4*)(x + (size_t)(i0 + r) * Dn + c * 4);

  float4 acc[4];
#pragma unroll
  for (int r = 0; r < 4; ++r) acc[r] = make_float4(0.f, 0.f, 0.f, 0.f);

  const float4* xq = (const float4*)x + (size_t)g * 32 * (Dn / 4) + c;
#pragma unroll 1
  for (int jj = 0; jj < 32; jj += 8) {
    float4 xj[8];
#pragma unroll
    for (int u = 0; u < 8; ++u) xj[u] = xq[(size_t)(jj + u) * (Dn / 4)];
#pragma unroll
    for (int u = 0; u < 8; ++u) {
#pragma unroll
      for (int r = 0; r < 4; ++r) {
        acc[r].x += fabsf(xi[r].x - xj[u].x);
        acc[r].y += fabsf(xi[r].y - xj[u].y);
        acc[r].z += fabsf(xi[r].z - xj[u].z);
        acc[r].w += fabsf(xi[r].w - xj[u].w);
      }
    }
  }
#pragma unroll
  for (int r = 0; r < 4; ++r) *(float4*)&red[g][r][c * 4] = acc[r];
  __syncthreads();

  // ---- Phase 2: reduce 32 j-groups; stage xs, wt_s ----
  if (t < 512) {
    const int r = t >> 7, d = t & 127;
    float s = 0.f;
#pragma unroll
    for (int gg = 0; gg < 32; ++gg) s += red[gg][r][d];
    dms[r][d] = s * (1.0f / 1024.0f);
    xs[r][d] = x[(size_t)(i0 + r) * Dn + d];
  } else if (t < 640) {
    wt_s[t - 512] = Wt[t - 512];
  }
  __syncthreads();

  // ---- Phase 3: tau (one wave per row, t<256) ----
  if (t < 256) {
    const int r = t >> 6, p = t & 63;
    float partial = xs[r][p] * wt_s[p] + xs[r][p + 64] * wt_s[p + 64];
#pragma unroll
    for (int off = 32; off; off >>= 1) partial += __shfl_xor(partial, off, 64);
    if (p == 0) {
      const float z = partial + bt[0];
      const float sp = fmaxf(z, 0.f) + log1pf(expf(-fabsf(z)));  // softplus
      tau_s[r] = 1.0f / (fmaxf(sp, 0.01f) + 1.0f);
    }
  }
  __syncthreads();

  // ---- Phase 4a: m = (Wd . dm + bd) / tau (t<256) ----
  if (t < 256) {
    const int h = t & 127;
    const int g4 = t >> 7;
    const int r0 = 2 * g4, r1 = 2 * g4 + 1;
    float m0 = bd[h], m1 = m0;
    const float4* w = (const float4*)(Wd + (size_t)h * Dn);
#pragma unroll 4
    for (int k4 = 0; k4 < Dn / 4; ++k4) {
      const float4 wv = w[k4];
      const int k = k4 * 4;
      m0 += wv.x * dms[r0][k] + wv.y * dms[r0][k + 1] + wv.z * dms[r0][k + 2] + wv.w * dms[r0][k + 3];
      m1 += wv.x * dms[r1][k] + wv.y * dms[r1][k + 1] + wv.z * dms[r1][k + 2] + wv.w * dms[r1][k + 3];
    }
    ms[r0][h] = m0 * tau_s[r0];
    ms[r1][h] = m1 * tau_s[r1];
  }
  __syncthreads();

  // ---- Phase 4b: y = relu(Wa . m + ba) + Wr . x + br (t<256) ----
  if (t < 256) {
    const int h = t & 127;
    const int g4 = t >> 7;
    const int r0 = 2 * g4, r1 = 2 * g4 + 1;
    float q0 = ba[h], q1 = q0, c0 = br[h], c1 = c0;
    const float4* wa = (const float4*)(Wa + (size_t)h * Dn);
    const float4* wr = (const float4*)(Wr + (size_t)h * Dn);
#pragma unroll 4
    for (int k4 = 0; k4 < Dn / 4; ++k4) {
      const float4 av = wa[k4];
      const float4 rv = wr[k4];
      const int k = k4 * 4;
      q0 += av.x * ms[r0][k] + av.y * ms[r0][k + 1] + av.z * ms[r0][k + 2] + av.w * ms[r0][k + 3];
      q1 += av.x * ms[r1][k] + av.y * ms[r1][k + 1] + av.z * ms[r1][k + 2] + av.w * ms[r1][k + 3];
      c0 += rv.x * xs[r0][k] + rv.y * xs[r0][k + 1] + rv.z * xs[r0][k + 2] + rv.w * xs[r0][k + 3];
      c1 += rv.x * xs[r1][k] + rv.y * xs[r1][k + 1] + rv.z * xs[r1][k + 2] + rv.w * xs[r1][k + 3];
    }
    ys[r0][h] = fmaxf(q0, 0.f) + c0;
    ys[r1][h] = fmaxf(q1, 0.f) + c1;
  }
  __syncthreads();

  // ---- Phase 5: LayerNorm (one wave per row, t<256) ----
  if (t < 256) {
    const int r = t >> 6, p = t & 63;
    const float v0 = ys[r][p], v1 = ys[r][p + 64];
    float s = v0 + v1;
    float q = v0 * v0 + v1 * v1;
#pragma unroll
    for (int off = 32; off; off >>= 1) {
      s += __shfl_xor(s, off, 64);
      q += __shfl_xor(q, off, 64);
    }
    const float mu = s * (1.0f / 128.0f);
    const float var = q * (1.0f / 128.0f) - mu * mu;
    const float rs = rsqrtf(var + 1e-5f);
    float* o = out + (size_t)(i0 + r) * Hn;
    o[p]      = (v0 - mu) * rs * gamma[p]      + beta[p];
    o[p + 64] = (v1 - mu) * rs * gamma[p + 64] + beta[p + 64];
  }
}

extern "C" void kernel_launch(void* const* d_in, const int* in_sizes, int n_in,
                              void* d_out, int out_size, void* d_ws, size_t ws_size,
                              hipStream_t stream) {
  const float* x     = (const float*)d_in[0];
  const float* Wd    = (const float*)d_in[1];
  const float* bd    = (const float*)d_in[2];
  const float* Wt    = (const float*)d_in[3];
  const float* bt    = (const float*)d_in[4];
  const float* Wa    = (const float*)d_in[5];
  const float* ba    = (const float*)d_in[6];
  const float* Wr    = (const float*)d_in[7];
  const float* br    = (const float*)d_in[8];
  const float* gamma = (const float*)d_in[9];
  const float* beta  = (const float*)d_in[10];
  float* out = (float*)d_out;

  fused_resd1<<<Bn / 4, 1024, 0, stream>>>(x, Wd, bd, Wt, bt, Wa, ba, Wr, br,
                                           gamma, beta, out);
  (void)in_sizes; (void)n_in; (void)out_size; (void)d_ws; (void)ws_size;
}